// Round 8
// baseline (228.247 us; speedup 1.0000x reference)
//
#include <hip/hip_runtime.h>
#include <hip/hip_fp16.h>

// GraphSAGE 3-layer forward, f32.
// CSR build: deg histogram (atomics, also emits per-edge rank) -> hierarchical
// scan -> atomic-free bucket fill (ushort esrc). Aggregation: fp16 gather
// (halved row traffic; fp16 rel err 2^-11 fits the error budget). GEMM: MFMA
// bf16 hi/lo 3-term split (~f32 precision); epilogue dual-writes f32 + fp16
// plane for the next layer's gather. d_out doubles as the rotating fp16
// scratch. deg zeroing via own kernel (rocclr fillBuffer cost 44us for 200KB).

#define DIN 96

typedef __attribute__((ext_vector_type(8))) short bf16x8;
typedef __attribute__((ext_vector_type(16))) float f32x16;

// ---- zero fill (replaces hipMemsetAsync's slow fill kernel) ----
__global__ void zero_deg_kernel(int* __restrict__ p, int n) {
    int i = blockIdx.x * blockDim.x + threadIdx.x;
    if (i < n) p[i] = 0;
}

// ---- degree histogram + per-edge rank ----
__global__ void deg_kernel(const int* __restrict__ dst, int* __restrict__ deg,
                           int* __restrict__ rank, int nE) {
    int i = blockIdx.x * blockDim.x + threadIdx.x;
    if (i < nE) rank[i] = atomicAdd(&deg[dst[i]], 1);
}

// ---- hierarchical exclusive scan, phase 1: per-block sums ----
__global__ void block_sum_kernel(const int* __restrict__ deg, int* __restrict__ bsum, int nN) {
    __shared__ int s[256];
    const int tid = threadIdx.x;
    int i = blockIdx.x * 256 + tid;
    s[tid] = (i < nN) ? deg[i] : 0;
    __syncthreads();
    for (int d = 128; d > 0; d >>= 1) {
        if (tid < d) s[tid] += s[tid + d];
        __syncthreads();
    }
    if (tid == 0) bsum[blockIdx.x] = s[0];
}

// ---- phase 2: exclusive scan of block sums (nB <= 256, single block) ----
__global__ void bsum_scan_kernel(int* __restrict__ bsum, int nB) {
    __shared__ int s[256];
    const int tid = threadIdx.x;
    int v = (tid < nB) ? bsum[tid] : 0;
    s[tid] = v;
    __syncthreads();
    for (int d = 1; d < 256; d <<= 1) {
        int t = (tid >= d) ? s[tid - d] : 0;
        __syncthreads();
        s[tid] += t;
        __syncthreads();
    }
    if (tid < nB) bsum[tid] = s[tid] - v;   // exclusive
}

// ---- phase 3: local exclusive scan + block base -> offs ----
__global__ void scan_apply_kernel(const int* __restrict__ deg, const int* __restrict__ bsum,
                                  int* __restrict__ offs, int nN) {
    __shared__ int s[256];
    const int tid = threadIdx.x;
    int i = blockIdx.x * 256 + tid;
    int v = (i < nN) ? deg[i] : 0;
    s[tid] = v;
    __syncthreads();
    for (int d = 1; d < 256; d <<= 1) {
        int t = (tid >= d) ? s[tid - d] : 0;
        __syncthreads();
        s[tid] += t;
        __syncthreads();
    }
    if (i < nN) offs[i] = bsum[blockIdx.x] + s[tid] - v;
}

// ---- bucket fill (atomic-free): esrc[offs[dst]+rank] = src ----
__global__ void bucket_kernel(const int* __restrict__ src, const int* __restrict__ dst,
                              const int* __restrict__ offs, const int* __restrict__ rank,
                              unsigned short* __restrict__ esrc, int nE) {
    int e = blockIdx.x * blockDim.x + threadIdx.x;
    if (e < nE) esrc[offs[dst[e]] + rank[e]] = (unsigned short)src[e];
}

// ---- f32 -> fp16 plane conversion (for layer-0 input) ----
__global__ void tof16_kernel(const float* __restrict__ x, __half* __restrict__ xf, int n8) {
    int i = blockIdx.x * blockDim.x + threadIdx.x;
    if (i >= n8) return;
    float4 f0 = *reinterpret_cast<const float4*>(x + (size_t)i * 8);
    float4 f1 = *reinterpret_cast<const float4*>(x + (size_t)i * 8 + 4);
    union { __half2 h2[4]; float4 raw; } o;
    o.h2[0] = __float22half2_rn(make_float2(f0.x, f0.y));
    o.h2[1] = __float22half2_rn(make_float2(f0.z, f0.w));
    o.h2[2] = __float22half2_rn(make_float2(f1.x, f1.y));
    o.h2[3] = __float22half2_rn(make_float2(f1.z, f1.w));
    *reinterpret_cast<float4*>(xf + (size_t)i * 8) = o.raw;
}

// ---- gather (fp16 rows): hmean[n,:] = mean over in-edges of hf[src,:] ----
// thread = (node, octet of 8 halves); 12 threads per node. 4x edge unroll.
__global__ void gather_kernel(const __half* __restrict__ hf, const unsigned short* __restrict__ esrc,
                              const int* __restrict__ offs, const int* __restrict__ deg,
                              float* __restrict__ hmean, int nN) {
    int idx = blockIdx.x * blockDim.x + threadIdx.x;
    if (idx >= nN * 12) return;
    int n = idx / 12;
    int q = idx - n * 12;
    const int beg = offs[n];
    const int dg = deg[n];
    const int end = beg + dg;
    const __half* hq = hf + q * 8;

    union H8 { float4 raw; __half2 h2[4]; };
    float a0[8], a1[8], a2[8], a3[8];
#pragma unroll
    for (int k = 0; k < 8; ++k) { a0[k] = 0.f; a1[k] = 0.f; a2[k] = 0.f; a3[k] = 0.f; }

    int j = beg;
    for (; j + 4 <= end; j += 4) {
        int s0 = esrc[j], s1 = esrc[j + 1], s2 = esrc[j + 2], s3 = esrc[j + 3];
        H8 v0, v1, v2, v3;
        v0.raw = *reinterpret_cast<const float4*>(hq + (size_t)s0 * DIN);
        v1.raw = *reinterpret_cast<const float4*>(hq + (size_t)s1 * DIN);
        v2.raw = *reinterpret_cast<const float4*>(hq + (size_t)s2 * DIN);
        v3.raw = *reinterpret_cast<const float4*>(hq + (size_t)s3 * DIN);
#pragma unroll
        for (int k = 0; k < 4; ++k) {
            float2 f0 = __half22float2(v0.h2[k]);
            float2 f1 = __half22float2(v1.h2[k]);
            float2 f2 = __half22float2(v2.h2[k]);
            float2 f3 = __half22float2(v3.h2[k]);
            a0[2 * k] += f0.x; a0[2 * k + 1] += f0.y;
            a1[2 * k] += f1.x; a1[2 * k + 1] += f1.y;
            a2[2 * k] += f2.x; a2[2 * k + 1] += f2.y;
            a3[2 * k] += f3.x; a3[2 * k + 1] += f3.y;
        }
    }
    for (; j < end; ++j) {
        int s0 = esrc[j];
        H8 v0;
        v0.raw = *reinterpret_cast<const float4*>(hq + (size_t)s0 * DIN);
#pragma unroll
        for (int k = 0; k < 4; ++k) {
            float2 f0 = __half22float2(v0.h2[k]);
            a0[2 * k] += f0.x; a0[2 * k + 1] += f0.y;
        }
    }
    const float r = 1.0f / (float)max(dg, 1);
    float4 o0, o1;
    o0.x = (a0[0] + a1[0] + a2[0] + a3[0]) * r;
    o0.y = (a0[1] + a1[1] + a2[1] + a3[1]) * r;
    o0.z = (a0[2] + a1[2] + a2[2] + a3[2]) * r;
    o0.w = (a0[3] + a1[3] + a2[3] + a3[3]) * r;
    o1.x = (a0[4] + a1[4] + a2[4] + a3[4]) * r;
    o1.y = (a0[5] + a1[5] + a2[5] + a3[5]) * r;
    o1.z = (a0[6] + a1[6] + a2[6] + a3[6]) * r;
    o1.w = (a0[7] + a1[7] + a2[7] + a3[7]) * r;
    float* op = hmean + (size_t)n * DIN + q * 8;
    *reinterpret_cast<float4*>(op) = o0;
    *reinterpret_cast<float4*>(op + 4) = o1;
}

// ---- f32x8 -> bf16 hi/lo (truncation split; hi+lo ~ 2^-17 rel error) ----
__device__ __forceinline__ void f32x8_to_hilo(const float4 f0, const float4 f1,
                                              bf16x8& hi, bf16x8& lo) {
    union { unsigned int u[4]; bf16x8 v; } H, L;
    const float fv[8] = {f0.x, f0.y, f0.z, f0.w, f1.x, f1.y, f1.z, f1.w};
#pragma unroll
    for (int i = 0; i < 4; ++i) {
        unsigned u0 = __float_as_uint(fv[2 * i]);
        unsigned u1 = __float_as_uint(fv[2 * i + 1]);
        unsigned h0 = u0 & 0xFFFF0000u;
        unsigned h1 = u1 & 0xFFFF0000u;
        H.u[i] = h1 | (h0 >> 16);
        float l0 = fv[2 * i]     - __uint_as_float(h0);
        float l1 = fv[2 * i + 1] - __uint_as_float(h1);
        L.u[i] = (__float_as_uint(l1) & 0xFFFF0000u) | (__float_as_uint(l0) >> 16);
    }
    hi = H.v; lo = L.v;
}

// ---- fused SAGE layer GEMM: MFMA 32x32x16 bf16, 3-term hi/lo split ----
// Block: 256 thr = 4 waves x 64 nodes; grid.y = DOUT/32 col-panels.
// WF16: also write fp16 plane (next layer's gather input).
template<int DOUT, bool RELU, bool WF16>
__global__ __launch_bounds__(256)
void sage_gemm_mfma(const float* __restrict__ hin, const float* __restrict__ hmean,
                    const float* __restrict__ wself, const float* __restrict__ wneigh,
                    const float* __restrict__ bias, float* __restrict__ hout,
                    __half* __restrict__ fout, int nN) {
    __shared__ unsigned int WhiS[32][100];   // 200 bf16 per row (192 + pad 8)
    __shared__ unsigned int WloS[32][100];

    const int tid = threadIdx.x;
    const int n0 = blockIdx.x * 256;
    const int ob = blockIdx.y * 32;

    // ---- stage weight panel: rows [ob, ob+32) of W' = [Wself | Wneigh] ----
    for (int c = tid; c < 32 * 24; c += 256) {
        int r = c / 24, k8 = c - (c / 24) * 24;
        const float* srcw = (k8 < 12) ? (wself + (size_t)(ob + r) * 96 + k8 * 8)
                                      : (wneigh + (size_t)(ob + r) * 96 + (k8 - 12) * 8);
        float4 f0 = *reinterpret_cast<const float4*>(srcw);
        float4 f1 = *reinterpret_cast<const float4*>(srcw + 4);
        bf16x8 hi, lo;
        f32x8_to_hilo(f0, f1, hi, lo);
        *reinterpret_cast<bf16x8*>(&WhiS[r][k8 * 4]) = hi;
        *reinterpret_cast<bf16x8*>(&WloS[r][k8 * 4]) = lo;
    }
    __syncthreads();

    const int lane = tid & 63;
    const int w = tid >> 6;           // wave 0..3
    const int col = lane & 31;        // output col within panel / A row within tile
    const int q = lane >> 5;          // 0..1 -> k-half of frag
    const int mbase = n0 + w * 64;

    const int nA0 = min(mbase + col, nN - 1);
    const int nA1 = min(mbase + 32 + col, nN - 1);

    f32x16 acc0 = {};
    f32x16 acc1 = {};

#pragma unroll
    for (int ks = 0; ks < 12; ++ks) {
        const int kk = ks * 16 + q * 8;                  // k in [0,192)
        const float* s0;
        const float* s1;
        if (kk < 96) {
            s0 = hin + (size_t)nA0 * 96 + kk;
            s1 = hin + (size_t)nA1 * 96 + kk;
        } else {
            s0 = hmean + (size_t)nA0 * 96 + (kk - 96);
            s1 = hmean + (size_t)nA1 * 96 + (kk - 96);
        }
        float4 a00 = *reinterpret_cast<const float4*>(s0);
        float4 a01 = *reinterpret_cast<const float4*>(s0 + 4);
        float4 a10 = *reinterpret_cast<const float4*>(s1);
        float4 a11 = *reinterpret_cast<const float4*>(s1 + 4);
        bf16x8 ahi0, alo0, ahi1, alo1;
        f32x8_to_hilo(a00, a01, ahi0, alo0);
        f32x8_to_hilo(a10, a11, ahi1, alo1);

        const bf16x8 whi = *reinterpret_cast<const bf16x8*>(&WhiS[col][ks * 8 + q * 4]);
        const bf16x8 wlo = *reinterpret_cast<const bf16x8*>(&WloS[col][ks * 8 + q * 4]);

        acc0 = __builtin_amdgcn_mfma_f32_32x32x16_bf16(ahi0, whi, acc0, 0, 0, 0);
        acc0 = __builtin_amdgcn_mfma_f32_32x32x16_bf16(ahi0, wlo, acc0, 0, 0, 0);
        acc0 = __builtin_amdgcn_mfma_f32_32x32x16_bf16(alo0, whi, acc0, 0, 0, 0);
        acc1 = __builtin_amdgcn_mfma_f32_32x32x16_bf16(ahi1, whi, acc1, 0, 0, 0);
        acc1 = __builtin_amdgcn_mfma_f32_32x32x16_bf16(ahi1, wlo, acc1, 0, 0, 0);
        acc1 = __builtin_amdgcn_mfma_f32_32x32x16_bf16(alo1, whi, acc1, 0, 0, 0);
    }

    // ---- epilogue: C/D layout col=lane&31, row=(i&3)+8*(i>>2)+4*q ----
    const float bv = bias[ob + col];
#pragma unroll
    for (int i = 0; i < 16; ++i) {
        const int row = (i & 3) + 8 * (i >> 2) + 4 * q;
        int n = mbase + row;
        if (n < nN) {
            float v = acc0[i] + bv;
            if (RELU) v = fmaxf(v, 0.f);
            hout[(size_t)n * DOUT + ob + col] = v;
            if (WF16) fout[(size_t)n * DOUT + ob + col] = __float2half_rn(v);
        }
        n = mbase + 32 + row;
        if (n < nN) {
            float v = acc1[i] + bv;
            if (RELU) v = fmaxf(v, 0.f);
            hout[(size_t)n * DOUT + ob + col] = v;
            if (WF16) fout[(size_t)n * DOUT + ob + col] = __float2half_rn(v);
        }
    }
}

extern "C" void kernel_launch(void* const* d_in, const int* in_sizes, int n_in,
                              void* d_out, int out_size, void* d_ws, size_t ws_size,
                              hipStream_t stream) {
    const float* x   = (const float*)d_in[0];
    const int*   src = (const int*)d_in[1];
    const int*   dst = (const int*)d_in[2];
    const float* ws0 = (const float*)d_in[3];
    const float* wn0 = (const float*)d_in[4];
    const float* b0  = (const float*)d_in[5];
    const float* ws1 = (const float*)d_in[6];
    const float* wn1 = (const float*)d_in[7];
    const float* b1  = (const float*)d_in[8];
    const float* ws2 = (const float*)d_in[9];
    const float* wn2 = (const float*)d_in[10];
    const float* b2  = (const float*)d_in[11];
    float* out = (float*)d_out;

    const int nN = in_sizes[0] / DIN;   // 50000
    const int nE = in_sizes[1];         // 800000
    const int nB = (nN + 255) / 256;    // scan blocks (<= 256)

    // workspace: deg[50048] offs[50048] bsum[256] rank[nE] (int)
    //            | esrc[nE] (ushort) | hmean,hA,hB [nN*96] (f32)
    int* deg  = (int*)d_ws;
    int* offs = deg + 50048;
    int* bsum = offs + 50048;
    int* rank = bsum + 256;
    unsigned short* esrc = (unsigned short*)(rank + nE);
    float* hmean = (float*)(esrc + nE);
    float* hA    = hmean + (size_t)nN * DIN;
    float* hB    = hA + (size_t)nN * DIN;

    // d_out (12.8MB) doubles as the rotating fp16 plane (9.6MB needed):
    // xf16 (tof16 -> gather0), hA_f16 (gemm0 -> gather1), hB_f16 (gemm1 ->
    // gather2); each dead before the next write; gemm2 overwrites all of d_out.
    __half* f16buf = (__half*)d_out;

    // ---- build CSR by dst (per call) ----
    zero_deg_kernel<<<nB, 256, 0, stream>>>(deg, nN);
    deg_kernel<<<(nE + 255) / 256, 256, 0, stream>>>(dst, deg, rank, nE);
    block_sum_kernel<<<nB, 256, 0, stream>>>(deg, bsum, nN);
    bsum_scan_kernel<<<1, 256, 0, stream>>>(bsum, nB);
    scan_apply_kernel<<<nB, 256, 0, stream>>>(deg, bsum, offs, nN);
    bucket_kernel<<<(nE + 255) / 256, 256, 0, stream>>>(src, dst, offs, rank, esrc, nE);

    const int ggrid = (nN * 12 + 255) / 256;
    const int cgrid = (nN * 12 + 255) / 256;   // nN*96/8 threads
    const int mblocks = (nN + 255) / 256;      // 196
    dim3 mgrid96(mblocks, 3);
    dim3 mgrid64(mblocks, 2);

    // ---- layer 0 ----
    tof16_kernel<<<cgrid, 256, 0, stream>>>(x, f16buf, nN * 12);
    gather_kernel<<<ggrid, 256, 0, stream>>>(f16buf, esrc, offs, deg, hmean, nN);
    sage_gemm_mfma<96, true, true><<<mgrid96, 256, 0, stream>>>(x, hmean, ws0, wn0, b0, hA, f16buf, nN);

    // ---- layer 1 ----
    gather_kernel<<<ggrid, 256, 0, stream>>>(f16buf, esrc, offs, deg, hmean, nN);
    sage_gemm_mfma<96, true, true><<<mgrid96, 256, 0, stream>>>(hA, hmean, ws1, wn1, b1, hB, f16buf, nN);

    // ---- layer 2 ----
    gather_kernel<<<ggrid, 256, 0, stream>>>(f16buf, esrc, offs, deg, hmean, nN);
    sage_gemm_mfma<64, false, false><<<mgrid64, 256, 0, stream>>>(hB, hmean, ws2, wn2, b2, out, nullptr, nN);
}

// Round 9
// 222.792 us; speedup vs baseline: 1.0245x; 1.0245x over previous
//
#include <hip/hip_runtime.h>
#include <hip/hip_fp16.h>

// GraphSAGE 3-layer forward, f32.
// CSR build: deg histogram (+per-edge rank) -> hierarchical scan ->
// atomic-free bucket (ushort esrc). Aggregation: fp16 gather -> fp16 hmean.
// GEMM: MFMA bf16 hi/lo 3-term split, ALL col-panels per block (weights in
// LDS once; A read once), A-self f32 / A-neigh fp16; epilogue dual-writes
// f32 + fp16 plane. d_out doubles as rotating fp16 scratch.

#define DIN 96

typedef __attribute__((ext_vector_type(8))) short bf16x8;
typedef __attribute__((ext_vector_type(16))) float f32x16;

// ---- zero fill ----
__global__ void zero_deg_kernel(int* __restrict__ p, int n) {
    int i = blockIdx.x * blockDim.x + threadIdx.x;
    if (i < n) p[i] = 0;
}

// ---- degree histogram + per-edge rank ----
__global__ void deg_kernel(const int* __restrict__ dst, int* __restrict__ deg,
                           int* __restrict__ rank, int nE) {
    int i = blockIdx.x * blockDim.x + threadIdx.x;
    if (i < nE) rank[i] = atomicAdd(&deg[dst[i]], 1);
}

// ---- hierarchical exclusive scan, phase 1: per-block sums ----
__global__ void block_sum_kernel(const int* __restrict__ deg, int* __restrict__ bsum, int nN) {
    __shared__ int s[256];
    const int tid = threadIdx.x;
    int i = blockIdx.x * 256 + tid;
    s[tid] = (i < nN) ? deg[i] : 0;
    __syncthreads();
    for (int d = 128; d > 0; d >>= 1) {
        if (tid < d) s[tid] += s[tid + d];
        __syncthreads();
    }
    if (tid == 0) bsum[blockIdx.x] = s[0];
}

// ---- phase 2: exclusive scan of block sums ----
__global__ void bsum_scan_kernel(int* __restrict__ bsum, int nB) {
    __shared__ int s[256];
    const int tid = threadIdx.x;
    int v = (tid < nB) ? bsum[tid] : 0;
    s[tid] = v;
    __syncthreads();
    for (int d = 1; d < 256; d <<= 1) {
        int t = (tid >= d) ? s[tid - d] : 0;
        __syncthreads();
        s[tid] += t;
        __syncthreads();
    }
    if (tid < nB) bsum[tid] = s[tid] - v;   // exclusive
}

// ---- phase 3: local exclusive scan + block base -> offs ----
__global__ void scan_apply_kernel(const int* __restrict__ deg, const int* __restrict__ bsum,
                                  int* __restrict__ offs, int nN) {
    __shared__ int s[256];
    const int tid = threadIdx.x;
    int i = blockIdx.x * 256 + tid;
    int v = (i < nN) ? deg[i] : 0;
    s[tid] = v;
    __syncthreads();
    for (int d = 1; d < 256; d <<= 1) {
        int t = (tid >= d) ? s[tid - d] : 0;
        __syncthreads();
        s[tid] += t;
        __syncthreads();
    }
    if (i < nN) offs[i] = bsum[blockIdx.x] + s[tid] - v;
}

// ---- bucket fill (atomic-free) ----
__global__ void bucket_kernel(const int* __restrict__ src, const int* __restrict__ dst,
                              const int* __restrict__ offs, const int* __restrict__ rank,
                              unsigned short* __restrict__ esrc, int nE) {
    int e = blockIdx.x * blockDim.x + threadIdx.x;
    if (e < nE) esrc[offs[dst[e]] + rank[e]] = (unsigned short)src[e];
}

// ---- f32 -> fp16 plane (layer-0 input) ----
__global__ void tof16_kernel(const float* __restrict__ x, __half* __restrict__ xf, int n8) {
    int i = blockIdx.x * blockDim.x + threadIdx.x;
    if (i >= n8) return;
    float4 f0 = *reinterpret_cast<const float4*>(x + (size_t)i * 8);
    float4 f1 = *reinterpret_cast<const float4*>(x + (size_t)i * 8 + 4);
    union { __half2 h2[4]; float4 raw; } o;
    o.h2[0] = __float22half2_rn(make_float2(f0.x, f0.y));
    o.h2[1] = __float22half2_rn(make_float2(f0.z, f0.w));
    o.h2[2] = __float22half2_rn(make_float2(f1.x, f1.y));
    o.h2[3] = __float22half2_rn(make_float2(f1.z, f1.w));
    *reinterpret_cast<float4*>(xf + (size_t)i * 8) = o.raw;
}

// ---- gather (fp16 rows -> fp16 hmean) ----
// thread = (node, octet of 8 halves); 12 threads per node. 4x edge unroll.
__global__ void gather_kernel(const __half* __restrict__ hf, const unsigned short* __restrict__ esrc,
                              const int* __restrict__ offs, const int* __restrict__ deg,
                              __half* __restrict__ hmean, int nN) {
    int idx = blockIdx.x * blockDim.x + threadIdx.x;
    if (idx >= nN * 12) return;
    int n = idx / 12;
    int q = idx - n * 12;
    const int beg = offs[n];
    const int dg = deg[n];
    const int end = beg + dg;
    const __half* hq = hf + q * 8;

    union H8 { float4 raw; __half2 h2[4]; };
    float a0[8], a1[8], a2[8], a3[8];
#pragma unroll
    for (int k = 0; k < 8; ++k) { a0[k] = 0.f; a1[k] = 0.f; a2[k] = 0.f; a3[k] = 0.f; }

    int j = beg;
    for (; j + 4 <= end; j += 4) {
        int s0 = esrc[j], s1 = esrc[j + 1], s2 = esrc[j + 2], s3 = esrc[j + 3];
        H8 v0, v1, v2, v3;
        v0.raw = *reinterpret_cast<const float4*>(hq + (size_t)s0 * DIN);
        v1.raw = *reinterpret_cast<const float4*>(hq + (size_t)s1 * DIN);
        v2.raw = *reinterpret_cast<const float4*>(hq + (size_t)s2 * DIN);
        v3.raw = *reinterpret_cast<const float4*>(hq + (size_t)s3 * DIN);
#pragma unroll
        for (int k = 0; k < 4; ++k) {
            float2 f0 = __half22float2(v0.h2[k]);
            float2 f1 = __half22float2(v1.h2[k]);
            float2 f2 = __half22float2(v2.h2[k]);
            float2 f3 = __half22float2(v3.h2[k]);
            a0[2 * k] += f0.x; a0[2 * k + 1] += f0.y;
            a1[2 * k] += f1.x; a1[2 * k + 1] += f1.y;
            a2[2 * k] += f2.x; a2[2 * k + 1] += f2.y;
            a3[2 * k] += f3.x; a3[2 * k + 1] += f3.y;
        }
    }
    for (; j < end; ++j) {
        int s0 = esrc[j];
        H8 v0;
        v0.raw = *reinterpret_cast<const float4*>(hq + (size_t)s0 * DIN);
#pragma unroll
        for (int k = 0; k < 4; ++k) {
            float2 f0 = __half22float2(v0.h2[k]);
            a0[2 * k] += f0.x; a0[2 * k + 1] += f0.y;
        }
    }
    const float r = 1.0f / (float)max(dg, 1);
    union H8 o;
    o.h2[0] = __float22half2_rn(make_float2((a0[0]+a1[0]+a2[0]+a3[0])*r, (a0[1]+a1[1]+a2[1]+a3[1])*r));
    o.h2[1] = __float22half2_rn(make_float2((a0[2]+a1[2]+a2[2]+a3[2])*r, (a0[3]+a1[3]+a2[3]+a3[3])*r));
    o.h2[2] = __float22half2_rn(make_float2((a0[4]+a1[4]+a2[4]+a3[4])*r, (a0[5]+a1[5]+a2[5]+a3[5])*r));
    o.h2[3] = __float22half2_rn(make_float2((a0[6]+a1[6]+a2[6]+a3[6])*r, (a0[7]+a1[7]+a2[7]+a3[7])*r));
    *reinterpret_cast<float4*>(hmean + (size_t)n * DIN + q * 8) = o.raw;
}

// ---- 8 x f32 -> bf16 hi/lo pack ----
__device__ __forceinline__ void fv8_to_hilo(const float* fv, bf16x8& hi, bf16x8& lo) {
    union { unsigned int u[4]; bf16x8 v; } H, L;
#pragma unroll
    for (int i = 0; i < 4; ++i) {
        unsigned u0 = __float_as_uint(fv[2 * i]);
        unsigned u1 = __float_as_uint(fv[2 * i + 1]);
        unsigned h0 = u0 & 0xFFFF0000u;
        unsigned h1 = u1 & 0xFFFF0000u;
        H.u[i] = h1 | (h0 >> 16);
        float l0 = fv[2 * i]     - __uint_as_float(h0);
        float l1 = fv[2 * i + 1] - __uint_as_float(h1);
        L.u[i] = (__float_as_uint(l1) & 0xFFFF0000u) | (__float_as_uint(l0) >> 16);
    }
    hi = H.v; lo = L.v;
}

// ---- fused SAGE layer GEMM v5: panel-fused MFMA ----
// Block: 256 thr = 4 waves x 64 nodes = 256 nodes; ALL DOUT cols per block.
// LDS: full W' = [Wself|Wneigh] (DOUT x 192) as bf16 hi+lo, pitch 100 uints.
// Wave: 2 M-subtiles of 32; per ks: A frags (f32 self / fp16 neigh) from
// global, NP weight b128 pairs from LDS, 6*NP MFMA. A read ONCE per layer.
template<int DOUT, int NP, bool RELU, bool WF16>
__global__ __launch_bounds__(256)
void sage_gemm_mfma(const float* __restrict__ hin, const __half* __restrict__ hm16,
                    const float* __restrict__ wself, const float* __restrict__ wneigh,
                    const float* __restrict__ bias, float* __restrict__ hout,
                    __half* __restrict__ fout, int nN) {
    __shared__ unsigned int WhiS[DOUT][100];
    __shared__ unsigned int WloS[DOUT][100];

    const int tid = threadIdx.x;
    const int n0 = blockIdx.x * 256;

    // stage full weight matrix as hi/lo bf16
    for (int c = tid; c < DOUT * 24; c += 256) {
        int r = c / 24, k8 = c - (c / 24) * 24;
        const float* srcw = (k8 < 12) ? (wself + (size_t)r * 96 + k8 * 8)
                                      : (wneigh + (size_t)r * 96 + (k8 - 12) * 8);
        float4 f0 = *reinterpret_cast<const float4*>(srcw);
        float4 f1 = *reinterpret_cast<const float4*>(srcw + 4);
        float fv[8] = {f0.x, f0.y, f0.z, f0.w, f1.x, f1.y, f1.z, f1.w};
        bf16x8 hi, lo;
        fv8_to_hilo(fv, hi, lo);
        *reinterpret_cast<bf16x8*>(&WhiS[r][k8 * 4]) = hi;
        *reinterpret_cast<bf16x8*>(&WloS[r][k8 * 4]) = lo;
    }
    __syncthreads();

    const int lane = tid & 63;
    const int w = tid >> 6;
    const int col = lane & 31;
    const int q = lane >> 5;
    const int mbase = n0 + w * 64;

    const int nA0 = min(mbase + col, nN - 1);
    const int nA1 = min(mbase + 32 + col, nN - 1);

    f32x16 acc[NP][2];
#pragma unroll
    for (int p = 0; p < NP; ++p) {
        f32x16 z = {};
        acc[p][0] = z;
        acc[p][1] = z;
    }

#pragma unroll
    for (int ks = 0; ks < 12; ++ks) {
        float fv0[8], fv1[8];
        if (ks < 6) {                       // self half: f32 rows
            const float* s0 = hin + (size_t)nA0 * 96 + ks * 16 + q * 8;
            const float* s1 = hin + (size_t)nA1 * 96 + ks * 16 + q * 8;
            float4 a = *reinterpret_cast<const float4*>(s0);
            float4 b = *reinterpret_cast<const float4*>(s0 + 4);
            float4 c = *reinterpret_cast<const float4*>(s1);
            float4 d = *reinterpret_cast<const float4*>(s1 + 4);
            fv0[0]=a.x; fv0[1]=a.y; fv0[2]=a.z; fv0[3]=a.w;
            fv0[4]=b.x; fv0[5]=b.y; fv0[6]=b.z; fv0[7]=b.w;
            fv1[0]=c.x; fv1[1]=c.y; fv1[2]=c.z; fv1[3]=c.w;
            fv1[4]=d.x; fv1[5]=d.y; fv1[6]=d.z; fv1[7]=d.w;
        } else {                            // neighbor half: fp16 rows
            const __half* s0 = hm16 + (size_t)nA0 * 96 + (ks - 6) * 16 + q * 8;
            const __half* s1 = hm16 + (size_t)nA1 * 96 + (ks - 6) * 16 + q * 8;
            union { float4 raw; __half2 h2[4]; } u0, u1;
            u0.raw = *reinterpret_cast<const float4*>(s0);
            u1.raw = *reinterpret_cast<const float4*>(s1);
#pragma unroll
            for (int k = 0; k < 4; ++k) {
                float2 f0 = __half22float2(u0.h2[k]);
                float2 f1 = __half22float2(u1.h2[k]);
                fv0[2 * k] = f0.x; fv0[2 * k + 1] = f0.y;
                fv1[2 * k] = f1.x; fv1[2 * k + 1] = f1.y;
            }
        }
        bf16x8 ahi0, alo0, ahi1, alo1;
        fv8_to_hilo(fv0, ahi0, alo0);
        fv8_to_hilo(fv1, ahi1, alo1);

#pragma unroll
        for (int p = 0; p < NP; ++p) {
            const bf16x8 whi = *reinterpret_cast<const bf16x8*>(&WhiS[p * 32 + col][ks * 8 + q * 4]);
            const bf16x8 wlo = *reinterpret_cast<const bf16x8*>(&WloS[p * 32 + col][ks * 8 + q * 4]);
            acc[p][0] = __builtin_amdgcn_mfma_f32_32x32x16_bf16(ahi0, whi, acc[p][0], 0, 0, 0);
            acc[p][0] = __builtin_amdgcn_mfma_f32_32x32x16_bf16(ahi0, wlo, acc[p][0], 0, 0, 0);
            acc[p][0] = __builtin_amdgcn_mfma_f32_32x32x16_bf16(alo0, whi, acc[p][0], 0, 0, 0);
            acc[p][1] = __builtin_amdgcn_mfma_f32_32x32x16_bf16(ahi1, whi, acc[p][1], 0, 0, 0);
            acc[p][1] = __builtin_amdgcn_mfma_f32_32x32x16_bf16(ahi1, wlo, acc[p][1], 0, 0, 0);
            acc[p][1] = __builtin_amdgcn_mfma_f32_32x32x16_bf16(alo1, whi, acc[p][1], 0, 0, 0);
        }
    }

    // epilogue: C/D layout col=lane&31, row=(i&3)+8*(i>>2)+4*q
#pragma unroll
    for (int p = 0; p < NP; ++p) {
        const int oc = p * 32 + col;
        const float bv = bias[oc];
#pragma unroll
        for (int i = 0; i < 16; ++i) {
            const int row = (i & 3) + 8 * (i >> 2) + 4 * q;
            int n = mbase + row;
            if (n < nN) {
                float v = acc[p][0][i] + bv;
                if (RELU) v = fmaxf(v, 0.f);
                hout[(size_t)n * DOUT + oc] = v;
                if (WF16) fout[(size_t)n * DOUT + oc] = __float2half_rn(v);
            }
            n = mbase + 32 + row;
            if (n < nN) {
                float v = acc[p][1][i] + bv;
                if (RELU) v = fmaxf(v, 0.f);
                hout[(size_t)n * DOUT + oc] = v;
                if (WF16) fout[(size_t)n * DOUT + oc] = __float2half_rn(v);
            }
        }
    }
}

extern "C" void kernel_launch(void* const* d_in, const int* in_sizes, int n_in,
                              void* d_out, int out_size, void* d_ws, size_t ws_size,
                              hipStream_t stream) {
    const float* x   = (const float*)d_in[0];
    const int*   src = (const int*)d_in[1];
    const int*   dst = (const int*)d_in[2];
    const float* ws0 = (const float*)d_in[3];
    const float* wn0 = (const float*)d_in[4];
    const float* b0  = (const float*)d_in[5];
    const float* ws1 = (const float*)d_in[6];
    const float* wn1 = (const float*)d_in[7];
    const float* b1  = (const float*)d_in[8];
    const float* ws2 = (const float*)d_in[9];
    const float* wn2 = (const float*)d_in[10];
    const float* b2  = (const float*)d_in[11];
    float* out = (float*)d_out;

    const int nN = in_sizes[0] / DIN;   // 50000
    const int nE = in_sizes[1];         // 800000
    const int nB = (nN + 255) / 256;    // scan blocks

    // workspace: deg[50048] offs[50048] bsum[256] rank[nE] (int)
    //            | esrc[nE] (ushort) | hm16[nN*96] (f16) | hA,hB [nN*96] (f32)
    int* deg  = (int*)d_ws;
    int* offs = deg + 50048;
    int* bsum = offs + 50048;
    int* rank = bsum + 256;
    unsigned short* esrc = (unsigned short*)(rank + nE);
    __half* hm16 = (__half*)(esrc + nE);
    float* hA    = (float*)(hm16 + (size_t)nN * DIN);
    float* hB    = hA + (size_t)nN * DIN;

    // d_out doubles as the rotating fp16 h-plane (9.6MB < 12.8MB):
    // x_f16 -> gather0; gemm0 f16 out -> gather1; gemm1 f16 out -> gather2;
    // each dead before next write; gemm2 overwrites all of d_out with f32 out.
    __half* f16buf = (__half*)d_out;

    // ---- build CSR by dst ----
    zero_deg_kernel<<<nB, 256, 0, stream>>>(deg, nN);
    deg_kernel<<<(nE + 255) / 256, 256, 0, stream>>>(dst, deg, rank, nE);
    block_sum_kernel<<<nB, 256, 0, stream>>>(deg, bsum, nN);
    bsum_scan_kernel<<<1, 256, 0, stream>>>(bsum, nB);
    scan_apply_kernel<<<nB, 256, 0, stream>>>(deg, bsum, offs, nN);
    bucket_kernel<<<(nE + 255) / 256, 256, 0, stream>>>(src, dst, offs, rank, esrc, nE);

    const int ggrid = (nN * 12 + 255) / 256;
    const int mgrid = (nN + 255) / 256;    // 196 blocks, 256 nodes each

    // ---- layer 0 ----
    tof16_kernel<<<ggrid, 256, 0, stream>>>(x, f16buf, nN * 12);
    gather_kernel<<<ggrid, 256, 0, stream>>>(f16buf, esrc, offs, deg, hm16, nN);
    sage_gemm_mfma<96, 3, true, true><<<mgrid, 256, 0, stream>>>(x, hm16, ws0, wn0, b0, hA, f16buf, nN);

    // ---- layer 1 ----
    gather_kernel<<<ggrid, 256, 0, stream>>>(f16buf, esrc, offs, deg, hm16, nN);
    sage_gemm_mfma<96, 3, true, true><<<mgrid, 256, 0, stream>>>(hA, hm16, ws1, wn1, b1, hB, f16buf, nN);

    // ---- layer 2 ----
    gather_kernel<<<ggrid, 256, 0, stream>>>(f16buf, esrc, offs, deg, hm16, nN);
    sage_gemm_mfma<64, 2, false, false><<<mgrid, 256, 0, stream>>>(hB, hm16, ws2, wn2, b2, out, nullptr, nN);
}